// Round 1
// baseline (8892.102 us; speedup 1.0000x reference)
//
#include <hip/hip_runtime.h>
#include <hip/hip_bf16.h>

// Problem constants (match reference)
constexpr int B  = 4;
constexpr int S  = 512;
constexpr int D  = 512;
constexpr int H  = 8;
constexpr int DK = 64;
constexpr int NL = 6;
constexpr int V  = 32000;
constexpr int FF = 2048;
constexpr int BS = B * S;   // 2048 token rows

// ---------------------------------------------------------------------------
// Wave/block reduction helpers (wave = 64 lanes on CDNA)
// ---------------------------------------------------------------------------
__device__ inline float wave_reduce_sum(float v) {
#pragma unroll
  for (int off = 32; off; off >>= 1) v += __shfl_xor(v, off, 64);
  return v;
}
__device__ inline float wave_reduce_max(float v) {
#pragma unroll
  for (int off = 32; off; off >>= 1) v = fmaxf(v, __shfl_xor(v, off, 64));
  return v;
}

// ---------------------------------------------------------------------------
// Embedding + positional encoding:  out[row, d] = emb[tok[row], d] + PE(row%S, d)
// PE[p,j] = sin(p / 10000^(2j/D)) for even j, cos(...) for odd j  (same j!)
// ---------------------------------------------------------------------------
__global__ void embed_pe(const int* __restrict__ tok, const float* __restrict__ emb,
                         float* __restrict__ out) {
  const int row = blockIdx.x;           // 0..BS-1
  const int s = row & (S - 1);          // S = 512 (pow2)
  const int id = tok[row];
  const float* e = emb + (long)id * D;
  float* o = out + (long)row * D;
  for (int d = threadIdx.x; d < D; d += blockDim.x) {
    float expo = (2.0f * (float)d) / (float)D;
    float ang = (float)s / powf(10000.0f, expo);
    float pe = (d & 1) ? cosf(ang) : sinf(ang);
    o[d] = e[d] + pe;
  }
}

// ---------------------------------------------------------------------------
// Tiled fp32 GEMM (row-major, NN):  C[M,N] = A[M,K] @ B[K,N] (+bias, +relu)
// BLK in {64,128}; 256 threads; per-thread tile RT x RT (RT = BLK/16).
// All M,N divisible by BLK; K divisible by 16 (true for every call site).
// ---------------------------------------------------------------------------
template <int BLK, bool BIAS, bool RELU>
__global__ __launch_bounds__(256) void gemm_nn(const float* __restrict__ A,
                                               const float* __restrict__ Bm,
                                               const float* __restrict__ bias,
                                               float* __restrict__ C,
                                               int M, int N, int K) {
  constexpr int RT = BLK / 16;          // 4 or 8
  constexpr int KT = 16;
  constexpr int AL = BLK * KT / 256;    // elements loaded per thread per tile (4 or 8)
  __shared__ float As[KT][BLK];         // stored k-major (transposed)
  __shared__ float Bs[KT][BLK];

  const int t = threadIdx.x;
  const int tx = t & 15, ty = t >> 4;
  const long row0 = (long)blockIdx.y * BLK;
  const long col0 = (long)blockIdx.x * BLK;

  const int ar = t / (KT / AL);         // A-tile row this thread loads
  const int ak = (t % (KT / AL)) * AL;  // A-tile k-offset
  const int br = t / (BLK / AL);        // B-tile k-row
  const int bc = (t % (BLK / AL)) * AL; // B-tile col-offset

  const float* Ap = A + (row0 + ar) * (long)K + ak;
  const float* Bp = Bm + (long)br * N + col0 + bc;

  float acc[RT][RT] = {};

  for (int k0 = 0; k0 < K; k0 += KT) {
    float4 av[AL / 4], bv[AL / 4];
#pragma unroll
    for (int u = 0; u < AL / 4; ++u) {
      av[u] = *(const float4*)(Ap + 4 * u);
      bv[u] = *(const float4*)(Bp + 4 * u);
    }
    __syncthreads();  // previous iteration's LDS reads complete
#pragma unroll
    for (int u = 0; u < AL / 4; ++u) {
      As[ak + 4 * u + 0][ar] = av[u].x;
      As[ak + 4 * u + 1][ar] = av[u].y;
      As[ak + 4 * u + 2][ar] = av[u].z;
      As[ak + 4 * u + 3][ar] = av[u].w;
      *(float4*)&Bs[br][bc + 4 * u] = bv[u];
    }
    __syncthreads();
#pragma unroll
    for (int kk = 0; kk < KT; ++kk) {
      float a[RT], b[RT];
#pragma unroll
      for (int u = 0; u < RT / 4; ++u) {
        *(float4*)&a[4 * u] = *(const float4*)&As[kk][ty * RT + 4 * u];
        *(float4*)&b[4 * u] = *(const float4*)&Bs[kk][tx * RT + 4 * u];
      }
#pragma unroll
      for (int i = 0; i < RT; ++i)
#pragma unroll
        for (int j = 0; j < RT; ++j) acc[i][j] = fmaf(a[i], b[j], acc[i][j]);
    }
    Ap += KT;
    Bp += (long)KT * N;
  }

#pragma unroll
  for (int i = 0; i < RT; ++i) {
    long r = row0 + ty * RT + i;
    float* Crow = C + r * (long)N + col0 + tx * RT;
#pragma unroll
    for (int j = 0; j < RT; ++j) {
      float val = acc[i][j];
      if (BIAS) val += bias[col0 + tx * RT + j];
      if (RELU) val = fmaxf(val, 0.0f);
      Crow[j] = val;
    }
  }
}

template <int BLK>
static void launch_gemm(const float* A, const float* Bm, const float* bias, float* C,
                        int M, int N, int K, bool relu, hipStream_t stream) {
  dim3 g(N / BLK, M / BLK), blk(256);
  if (bias && relu)
    gemm_nn<BLK, true, true><<<g, blk, 0, stream>>>(A, Bm, bias, C, M, N, K);
  else if (bias)
    gemm_nn<BLK, true, false><<<g, blk, 0, stream>>>(A, Bm, bias, C, M, N, K);
  else
    gemm_nn<BLK, false, false><<<g, blk, 0, stream>>>(A, Bm, nullptr, C, M, N, K);
}

// ---------------------------------------------------------------------------
// Attention scores: sc[b,h,q,k] = dot(q[b,q,h,:], k[b,k,h,:]) / 8  (+causal)
// q,k layout: [B,S,H,DK] contiguous (== [B,S,D] after projection).
// Grid: (S/32, S/32, B*H), 256 threads; block computes a 32x32 tile.
// ---------------------------------------------------------------------------
template <bool CAUSAL>
__global__ __launch_bounds__(256) void attn_scores(const float* __restrict__ q,
                                                   const float* __restrict__ k,
                                                   float* __restrict__ sc) {
  const int bh = blockIdx.z;            // b*H + h
  const int b = bh >> 3, h = bh & 7;    // H = 8
  const int q0 = blockIdx.y * 32, k0 = blockIdx.x * 32;
  const int t = threadIdx.x;
  const int tk = t & 31, tq = t >> 5;   // tq 0..7

  if (CAUSAL && k0 > q0 + 31) {         // fully masked tile
#pragma unroll
    for (int r = 0; r < 4; ++r) {
      int qg = q0 + tq + 8 * r;
      sc[((long)bh * S + qg) * S + k0 + tk] = -1e9f;
    }
    return;
  }

  __shared__ float Qs[32][65];          // +1 pad: kills stride-64 bank conflicts
  __shared__ float Ks[32][65];
  {
    const int lr = t >> 3;              // 0..31
    const int lc = (t & 7) * 8;         // 0..56
    const float* qp = q + ((long)(b * S + q0 + lr) * H + h) * DK + lc;
    const float* kp = k + ((long)(b * S + k0 + lr) * H + h) * DK + lc;
    float4 qa = *(const float4*)qp, qb = *(const float4*)(qp + 4);
    float4 ka = *(const float4*)kp, kb = *(const float4*)(kp + 4);
    Qs[lr][lc + 0] = qa.x; Qs[lr][lc + 1] = qa.y; Qs[lr][lc + 2] = qa.z; Qs[lr][lc + 3] = qa.w;
    Qs[lr][lc + 4] = qb.x; Qs[lr][lc + 5] = qb.y; Qs[lr][lc + 6] = qb.z; Qs[lr][lc + 7] = qb.w;
    Ks[lr][lc + 0] = ka.x; Ks[lr][lc + 1] = ka.y; Ks[lr][lc + 2] = ka.z; Ks[lr][lc + 3] = ka.w;
    Ks[lr][lc + 4] = kb.x; Ks[lr][lc + 5] = kb.y; Ks[lr][lc + 6] = kb.z; Ks[lr][lc + 7] = kb.w;
  }
  __syncthreads();

  float acc[4] = {};
#pragma unroll
  for (int d = 0; d < DK; ++d) {
    float kv = Ks[tk][d];
    acc[0] = fmaf(Qs[tq][d], kv, acc[0]);
    acc[1] = fmaf(Qs[tq + 8][d], kv, acc[1]);
    acc[2] = fmaf(Qs[tq + 16][d], kv, acc[2]);
    acc[3] = fmaf(Qs[tq + 24][d], kv, acc[3]);
  }
#pragma unroll
  for (int r = 0; r < 4; ++r) {
    int qg = q0 + tq + 8 * r, kg = k0 + tk;
    float vv = acc[r] * 0.125f;                       // 1/sqrt(64)
    if (CAUSAL && kg > qg) vv = -1e9f;
    sc[((long)bh * S + qg) * S + kg] = vv;
  }
}

// ---------------------------------------------------------------------------
// Row softmax, in place. One block (256 threads) per row of length L.
// Used for scores rows (L=S) and final output rows (L=V).
// ---------------------------------------------------------------------------
__global__ __launch_bounds__(256) void softmax_rows(float* __restrict__ data, int L) {
  __shared__ float red[4];
  float* p = data + (long)blockIdx.x * L;
  const int tid = threadIdx.x;

  float m = -1e30f;
  for (int i = tid; i < L; i += 256) m = fmaxf(m, p[i]);
  m = wave_reduce_max(m);
  if ((tid & 63) == 0) red[tid >> 6] = m;
  __syncthreads();
  m = fmaxf(fmaxf(red[0], red[1]), fmaxf(red[2], red[3]));
  __syncthreads();

  float s = 0.0f;
  for (int i = tid; i < L; i += 256) {
    float e = expf(p[i] - m);
    p[i] = e;
    s += e;
  }
  s = wave_reduce_sum(s);
  if ((tid & 63) == 0) red[tid >> 6] = s;
  __syncthreads();
  s = (red[0] + red[1]) + (red[2] + red[3]);
  float inv = 1.0f / s;
  for (int i = tid; i < L; i += 256) p[i] *= inv;
}

// ---------------------------------------------------------------------------
// PV: out[b,q,h,:] = sum_k sc[b,h,q,k] * v[b,k,h,:]
// Grid: (S/32, B*H); block computes 32 q-rows x DK cols.
// ---------------------------------------------------------------------------
__global__ __launch_bounds__(256) void attn_pv(const float* __restrict__ sc,
                                               const float* __restrict__ v,
                                               float* __restrict__ out) {
  const int bh = blockIdx.y;
  const int b = bh >> 3, h = bh & 7;
  const int q0 = blockIdx.x * 32;
  const int t = threadIdx.x;
  const int col = t & 63, rg = t >> 6;  // rg 0..3

  __shared__ float Ps[32][33];
  __shared__ float Vs[32][64];

  const int pr = t >> 3, pc = (t & 7) * 4;  // scores tile loads (32x32)
  const int vr = t >> 3, vc = (t & 7) * 8;  // v tile loads (32x64)

  float acc[8] = {};
  for (int kc = 0; kc < S; kc += 32) {
    float4 pv4 = *(const float4*)(sc + ((long)bh * S + q0 + pr) * S + kc + pc);
    const float* vp = v + ((long)(b * S + kc + vr) * H + h) * DK + vc;
    float4 v0 = *(const float4*)vp;
    float4 v1 = *(const float4*)(vp + 4);
    __syncthreads();
    Ps[pr][pc + 0] = pv4.x; Ps[pr][pc + 1] = pv4.y;
    Ps[pr][pc + 2] = pv4.z; Ps[pr][pc + 3] = pv4.w;
    *(float4*)&Vs[vr][vc] = v0;
    *(float4*)&Vs[vr][vc + 4] = v1;
    __syncthreads();
#pragma unroll
    for (int kk = 0; kk < 32; ++kk) {
      float vv = Vs[kk][col];
#pragma unroll
      for (int r = 0; r < 8; ++r) acc[r] = fmaf(Ps[rg + 4 * r][kk], vv, acc[r]);
    }
  }
#pragma unroll
  for (int r = 0; r < 8; ++r) {
    int qg = q0 + rg + 4 * r;
    out[((long)(b * S + qg) * H + h) * DK + col] = acc[r];
  }
}

// ---------------------------------------------------------------------------
// x = LayerNorm(x + r), rows of length D=512. One block per row.
// ---------------------------------------------------------------------------
__global__ __launch_bounds__(256) void add_ln(float* __restrict__ x,
                                              const float* __restrict__ r) {
  __shared__ float red[4];
  const int tid = threadIdx.x;
  float* p = x + (long)blockIdx.x * D;
  const float* a = r + (long)blockIdx.x * D;

  float v0 = p[tid] + a[tid];
  float v1 = p[tid + 256] + a[tid + 256];

  float s = v0 + v1;
  s = wave_reduce_sum(s);
  if ((tid & 63) == 0) red[tid >> 6] = s;
  __syncthreads();
  float mu = ((red[0] + red[1]) + (red[2] + red[3])) * (1.0f / (float)D);
  __syncthreads();

  float d0 = v0 - mu, d1 = v1 - mu;
  float q2 = d0 * d0 + d1 * d1;
  q2 = wave_reduce_sum(q2);
  if ((tid & 63) == 0) red[tid >> 6] = q2;
  __syncthreads();
  float var = ((red[0] + red[1]) + (red[2] + red[3])) * (1.0f / (float)D);
  float inv = rsqrtf(var + 1e-5f);
  p[tid] = d0 * inv;
  p[tid + 256] = d1 * inv;
}

// ---------------------------------------------------------------------------
// Host-side orchestration
// ---------------------------------------------------------------------------
extern "C" void kernel_launch(void* const* d_in, const int* in_sizes, int n_in,
                              void* d_out, int out_size, void* d_ws, size_t ws_size,
                              hipStream_t stream) {
  const int* src        = (const int*)d_in[0];
  const int* trg        = (const int*)d_in[1];
  const float* src_emb  = (const float*)d_in[2];
  const float* trg_emb  = (const float*)d_in[3];
  const float* enc_qkvo = (const float*)d_in[4];
  const float* enc_w1   = (const float*)d_in[5];
  const float* enc_b1   = (const float*)d_in[6];
  const float* enc_w2   = (const float*)d_in[7];
  const float* enc_b2   = (const float*)d_in[8];
  const float* dec_self = (const float*)d_in[9];
  const float* dec_crs  = (const float*)d_in[10];
  const float* dec_w1   = (const float*)d_in[11];
  const float* dec_b1   = (const float*)d_in[12];
  const float* dec_w2   = (const float*)d_in[13];
  const float* dec_b2   = (const float*)d_in[14];
  const float* out_w    = (const float*)d_in[15];
  const float* out_b    = (const float*)d_in[16];
  float* out = (float*)d_out;

  // Residual streams live in d_ws (only 8.4 MB needed there).
  float* x = (float*)d_ws;        // [BS, D] encoder stream
  float* y = x + (long)BS * D;    // [BS, D] decoder stream

  // All other scratch lives inside d_out (65.5M floats); every one of these
  // is dead before the final logits GEMM overwrites d_out, and that GEMM
  // reads only y (in d_ws) + weights.
  float* q      = out;                         // [BS, D]
  float* k      = q + (long)BS * D;            // [BS, D]   (also "tmp")
  float* v      = k + (long)BS * D;            // [BS, D]
  float* scores = v + (long)BS * D;            // [B,H,S,S]
  float* mid    = scores + (long)B * H * S * S;// [BS, FF]
  float* att    = q;                           // PV output reuses q
  float* tmp    = k;                           // proj/FFN output reuses k

  auto mha = [&](float* xq, float* xkv, const float* w4, bool causal, float* dst) {
    launch_gemm<64>(xq,  w4 + 0L * D * D, nullptr, q, BS, D, D, false, stream);
    launch_gemm<64>(xkv, w4 + 1L * D * D, nullptr, k, BS, D, D, false, stream);
    launch_gemm<64>(xkv, w4 + 2L * D * D, nullptr, v, BS, D, D, false, stream);
    if (causal)
      attn_scores<true><<<dim3(S / 32, S / 32, B * H), 256, 0, stream>>>(q, k, scores);
    else
      attn_scores<false><<<dim3(S / 32, S / 32, B * H), 256, 0, stream>>>(q, k, scores);
    softmax_rows<<<B * H * S, 256, 0, stream>>>(scores, S);
    attn_pv<<<dim3(S / 32, B * H), 256, 0, stream>>>(scores, v, att);
    launch_gemm<64>(att, w4 + 3L * D * D, nullptr, tmp, BS, D, D, false, stream);
    add_ln<<<BS, 256, 0, stream>>>(dst, tmp);
  };

  auto ffn = [&](float* xx, const float* w1, const float* b1,
                 const float* w2, const float* b2) {
    launch_gemm<128>(xx, w1, b1, mid, BS, FF, D, true, stream);
    launch_gemm<64>(mid, w2, b2, tmp, BS, D, FF, false, stream);
    add_ln<<<BS, 256, 0, stream>>>(xx, tmp);
  };

  embed_pe<<<BS, 256, 0, stream>>>(src, src_emb, x);
  embed_pe<<<BS, 256, 0, stream>>>(trg, trg_emb, y);

  for (int i = 0; i < NL; ++i) {
    mha(x, x, enc_qkvo + (long)i * 4 * D * D, false, x);
    ffn(x, enc_w1 + (long)i * D * FF, enc_b1 + (long)i * FF,
        enc_w2 + (long)i * FF * D, enc_b2 + (long)i * D);
  }
  for (int i = 0; i < NL; ++i) {
    mha(y, y, dec_self + (long)i * 4 * D * D, true, y);
    mha(y, x, dec_crs + (long)i * 4 * D * D, false, y);
    ffn(y, dec_w1 + (long)i * D * FF, dec_b1 + (long)i * FF,
        dec_w2 + (long)i * FF * D, dec_b2 + (long)i * D);
  }

  // logits = y @ out_w + out_b  -> overwrite all of d_out, then softmax rows
  launch_gemm<128>(y, out_w, out_b, out, BS, V, D, false, stream);
  softmax_rows<<<BS, 256, 0, stream>>>(out, V);
}